// Round 1
// baseline (9560.516 us; speedup 1.0000x reference)
//
#include <hip/hip_runtime.h>
#include <hip/hip_bf16.h>

// Problem constants (match reference)
constexpr int Bsz = 32;
constexpr int T   = 4096;
constexpr int P   = 64;
constexpr int IN  = 128;
constexpr int H   = 256;
constexpr long M  = (long)Bsz * T;   // 131072 rows

// ---------------------------------------------------------------------------
// K1/K3: out[m][j] = sum_c X[m][c] * W[j][c] + b1[j] + b2[j]
// X: [M][K] row-major, W: [H][K] row-major, out: [M][H]
// Block: 256 threads, computes 16 rows x 256 cols. W staged through LDS in
// 32-float K-chunks (stride-33 padding -> conflict-free b32 reads).
// ---------------------------------------------------------------------------
template <int K>
__global__ __launch_bounds__(256) void gemm_pre(
    const float* __restrict__ X, const float* __restrict__ W,
    const float* __restrict__ b1, const float* __restrict__ b2,
    float* __restrict__ out) {
  constexpr int K4 = K / 4;
  __shared__ float4 a4[16][K4];        // A tile (16 rows x K) : 8/16 KB
  __shared__ float  wch[256][33];      // W chunk (256 rows x 32), +1 pad
  const int tid = threadIdx.x;
  const long m0 = (long)blockIdx.x * 16;

  // Load A tile (coalesced float4)
  const float4* X4 = (const float4*)X;
#pragma unroll
  for (int i = 0; i < (16 * K4) / 256; ++i) {
    int idx = tid + 256 * i;
    int r = idx / K4, c = idx % K4;
    a4[r][c] = X4[(m0 + r) * K4 + c];
  }

  const int j = tid;                   // output column (0..255)
  const float bsum = b1[j] + b2[j];
  float acc[16];
#pragma unroll
  for (int r = 0; r < 16; ++r) acc[r] = 0.f;

  const float4* W4v = (const float4*)W;
  for (int kc = 0; kc < K4; kc += 8) { // 32-float K chunks
    __syncthreads();                   // protect wch (and a4 on first iter)
#pragma unroll
    for (int i = 0; i < 8; ++i) {
      int idx = tid + 256 * i;         // 2048 f4 per chunk
      int jr = idx >> 3, c = idx & 7;
      float4 t4 = W4v[(long)jr * K4 + kc + c];
      wch[jr][4 * c + 0] = t4.x; wch[jr][4 * c + 1] = t4.y;
      wch[jr][4 * c + 2] = t4.z; wch[jr][4 * c + 3] = t4.w;
    }
    __syncthreads();
#pragma unroll
    for (int i4 = 0; i4 < 8; ++i4) {
      float wx = wch[j][4 * i4 + 0], wy = wch[j][4 * i4 + 1];
      float wz = wch[j][4 * i4 + 2], ww = wch[j][4 * i4 + 3];
#pragma unroll
      for (int r = 0; r < 16; ++r) {
        float4 av = a4[r][kc + i4];    // lane-uniform broadcast
        acc[r] += wx * av.x + wy * av.y + wz * av.z + ww * av.w;
      }
    }
  }
#pragma unroll
  for (int r = 0; r < 16; ++r)
    out[(m0 + r) * H + j] = acc[r] + bsum;
}

// ---------------------------------------------------------------------------
// K2/K4: sequential scan.  One workgroup per batch element.
// 512 threads: j = tid&255 (output neuron), half = tid>>8 (K-half).
// Each thread keeps 128 floats of W_hh row j in VGPRs (32 x float4).
// h[256] in LDS; two-half partials reduced through LDS; 2 barriers/step.
// pre is prefetched 2 steps ahead (HBM latency ~900 cyc vs ~700 cyc/step).
// ---------------------------------------------------------------------------
__global__ __launch_bounds__(512, 2) void rnn_scan(
    const float* __restrict__ pre, const float* __restrict__ W_hh,
    float* __restrict__ hout) {
  __shared__ float h_lds[H];
  __shared__ float part[2][H];
  const int tid  = threadIdx.x;
  const int j    = tid & (H - 1);
  const int half = tid >> 8;          // wave-uniform (waves 0-3 / 4-7)
  const int b    = blockIdx.x;

  // W_hh row j, half `half` -> registers (fully unrolled => stays in VGPRs)
  const float4* W4 = (const float4*)W_hh;
  float4 w[32];
#pragma unroll
  for (int i = 0; i < 32; ++i) w[i] = W4[(long)j * (H / 4) + half * 32 + i];

  if (tid < H) h_lds[tid] = 0.f;      // h0 = 0

  const long base = ((long)b * T) * H + j;
  float p0 = 0.f, p1 = 0.f;
  if (half == 0) { p0 = pre[base]; p1 = pre[base + H]; }
  __syncthreads();

  const float4* hv4 = (const float4*)h_lds;
#pragma unroll 1
  for (int t = 0; t < T; ++t) {
    float p2 = 0.f;
    if (half == 0 && t + 2 < T) p2 = pre[base + (long)(t + 2) * H];

    float ax = 0.f, ay = 0.f, az = 0.f, aw = 0.f;  // 4 chains, no dep stall
#pragma unroll
    for (int i = 0; i < 32; ++i) {
      float4 h4 = hv4[half * 32 + i];              // b128 broadcast
      ax += w[i].x * h4.x; ay += w[i].y * h4.y;
      az += w[i].z * h4.z; aw += w[i].w * h4.w;
    }
    part[half][j] = (ax + ay) + (az + aw);
    __syncthreads();
    if (half == 0) {
      float hn = tanhf(p0 + part[0][j] + part[1][j]);
      h_lds[j] = hn;
      hout[base + (long)t * H] = hn;               // coalesced 1KB
      p0 = p1; p1 = p2;
    }
    __syncthreads();
  }
}

// ---------------------------------------------------------------------------
// K5: out[m][p] = sigmoid( sum_j h2[m][j]*fcW[p][j] + fcb[p] )
// Block: 256 threads = 64 p-columns x 4 row-groups; 16-row h2 tile in LDS;
// fcW read from global (64 KB, L1/L2-hot).
// ---------------------------------------------------------------------------
__global__ __launch_bounds__(256) void fc_sigmoid(
    const float* __restrict__ h2, const float* __restrict__ fcW,
    const float* __restrict__ fcb, float* __restrict__ out) {
  __shared__ float h2l[16][H];        // 16 KB
  const int tid = threadIdx.x;
  const long m0 = (long)blockIdx.x * 16;

  const float4* H4 = (const float4*)h2;
#pragma unroll
  for (int i = 0; i < 4; ++i) {
    int idx = tid + 256 * i;          // f4 index: r = idx/64, c4 = idx%64
    int r = idx >> 6, c4 = idx & 63;
    *(float4*)&h2l[r][4 * c4] = H4[(m0 + r) * (H / 4) + c4];
  }
  __syncthreads();

  const int p = tid & 63, rq = tid >> 6;   // rq wave-uniform
  const float4* W4 = (const float4*)fcW;
  float acc[4] = {0.f, 0.f, 0.f, 0.f};
#pragma unroll 8
  for (int c4 = 0; c4 < H / 4; ++c4) {
    float4 wv = W4[(long)p * (H / 4) + c4];
#pragma unroll
    for (int k = 0; k < 4; ++k) {
      float4 av = *(const float4*)&h2l[rq * 4 + k][4 * c4];  // broadcast
      acc[k] += wv.x * av.x + wv.y * av.y + wv.z * av.z + wv.w * av.w;
    }
  }
  const float bb = fcb[p];
#pragma unroll
  for (int k = 0; k < 4; ++k) {
    float x = acc[k] + bb;
    out[(m0 + rq * 4 + k) * P + p] = 1.f / (1.f + __expf(-x));
  }
}

// ---------------------------------------------------------------------------
extern "C" void kernel_launch(void* const* d_in, const int* in_sizes, int n_in,
                              void* d_out, int out_size, void* d_ws, size_t ws_size,
                              hipStream_t stream) {
  const float* input = (const float*)d_in[0];
  const float* W_ih0 = (const float*)d_in[1];
  const float* W_hh0 = (const float*)d_in[2];
  const float* b_ih0 = (const float*)d_in[3];
  const float* b_hh0 = (const float*)d_in[4];
  const float* W_ih1 = (const float*)d_in[5];
  const float* W_hh1 = (const float*)d_in[6];
  const float* b_ih1 = (const float*)d_in[7];
  const float* b_hh1 = (const float*)d_in[8];
  const float* fc_W  = (const float*)d_in[9];
  const float* fc_b  = (const float*)d_in[10];
  float* out = (float*)d_out;

  // Workspace: two [M][H] fp32 buffers (134 MB each, 268 MB total).
  // bufA: pre0 -> pre1 ; bufB: h1 -> h2   (lifetimes don't overlap)
  float* bufA = (float*)d_ws;
  float* bufB = bufA + (size_t)M * H;

  // K1: pre0 = input . W_ih0^T + (b_ih0 + b_hh0)
  gemm_pre<IN><<<(int)(M / 16), 256, 0, stream>>>(input, W_ih0, b_ih0, b_hh0, bufA);
  // K2: layer-0 scan -> h1
  rnn_scan<<<Bsz, 512, 0, stream>>>(bufA, W_hh0, bufB);
  // K3: pre1 = h1 . W_ih1^T + (b_ih1 + b_hh1)
  gemm_pre<H><<<(int)(M / 16), 256, 0, stream>>>(bufB, W_ih1, b_ih1, b_hh1, bufA);
  // K4: layer-1 scan -> h2
  rnn_scan<<<Bsz, 512, 0, stream>>>(bufA, W_hh1, bufB);
  // K5: FC + sigmoid -> out
  fc_sigmoid<<<(int)(M / 16), 256, 0, stream>>>(bufB, fc_W, fc_b, out);
}

// Round 3
// 8738.908 us; speedup vs baseline: 1.0940x; 1.0940x over previous
//
#include <hip/hip_runtime.h>
#include <hip/hip_bf16.h>

// Problem constants (match reference)
constexpr int Bsz = 32;
constexpr int T   = 4096;
constexpr int P   = 64;
constexpr int IN  = 128;
constexpr int H   = 256;
constexpr long M  = (long)Bsz * T;   // 131072 rows

// ---------------------------------------------------------------------------
// K1/K3: out[m][j] = sum_c X[m][c] * W[j][c] + b1[j] + b2[j]
// X: [M][K] row-major, W: [H][K] row-major, out: [M][H]
// ---------------------------------------------------------------------------
template <int K>
__global__ __launch_bounds__(256) void gemm_pre(
    const float* __restrict__ X, const float* __restrict__ W,
    const float* __restrict__ b1, const float* __restrict__ b2,
    float* __restrict__ out) {
  constexpr int K4 = K / 4;
  __shared__ float4 a4[16][K4];        // A tile (16 rows x K) : 8/16 KB
  __shared__ float  wch[256][33];      // W chunk (256 rows x 32), +1 pad
  const int tid = threadIdx.x;
  const long m0 = (long)blockIdx.x * 16;

  const float4* X4 = (const float4*)X;
#pragma unroll
  for (int i = 0; i < (16 * K4) / 256; ++i) {
    int idx = tid + 256 * i;
    int r = idx / K4, c = idx % K4;
    a4[r][c] = X4[(m0 + r) * K4 + c];
  }

  const int j = tid;                   // output column (0..255)
  const float bsum = b1[j] + b2[j];
  float acc[16];
#pragma unroll
  for (int r = 0; r < 16; ++r) acc[r] = 0.f;

  const float4* W4v = (const float4*)W;
  for (int kc = 0; kc < K4; kc += 8) { // 32-float K chunks
    __syncthreads();
#pragma unroll
    for (int i = 0; i < 8; ++i) {
      int idx = tid + 256 * i;
      int jr = idx >> 3, c = idx & 7;
      float4 t4 = W4v[(long)jr * K4 + kc + c];
      wch[jr][4 * c + 0] = t4.x; wch[jr][4 * c + 1] = t4.y;
      wch[jr][4 * c + 2] = t4.z; wch[jr][4 * c + 3] = t4.w;
    }
    __syncthreads();
#pragma unroll
    for (int i4 = 0; i4 < 8; ++i4) {
      float wx = wch[j][4 * i4 + 0], wy = wch[j][4 * i4 + 1];
      float wz = wch[j][4 * i4 + 2], ww = wch[j][4 * i4 + 3];
#pragma unroll
      for (int r = 0; r < 16; ++r) {
        float4 av = a4[r][kc + i4];
        acc[r] += wx * av.x + wy * av.y + wz * av.z + ww * av.w;
      }
    }
  }
#pragma unroll
  for (int r = 0; r < 16; ++r)
    out[(m0 + r) * H + j] = acc[r] + bsum;
}

// ---------------------------------------------------------------------------
// K2/K4: sequential scan.  One workgroup per batch element.
// 1024 threads (16 waves, 4/SIMD): j = tid&255 (output neuron),
// q = tid>>8 (K-quarter).  Each thread keeps 64 floats of W_hh row j in
// VGPRs (pinned via an opaque asm barrier on scalar floats so the backend
// cannot rematerialize the invariant loads -- R1 showed VGPR_Count=84,
// i.e. W was re-read from L2 every step, ~2460 cyc/step).  h[256] in LDS;
// 4-way partial reduction through LDS; 2 barriers/step; pre prefetched
// 2 steps ahead.
// ---------------------------------------------------------------------------
__global__ __launch_bounds__(1024, 4) void rnn_scan(
    const float* __restrict__ pre, const float* __restrict__ W_hh,
    float* __restrict__ hout) {
  __shared__ float h_lds[H];
  __shared__ float part[4][H];
  const int tid = threadIdx.x;
  const int j   = tid & (H - 1);
  const int q   = tid >> 8;           // wave-uniform (4 waves per quarter)
  const int b   = blockIdx.x;

  // W_hh row j, quarter q -> 64 floats in VGPRs
  const float4* W4 = (const float4*)W_hh;
  float wx[16], wy[16], wz[16], ww[16];
#pragma unroll
  for (int i = 0; i < 16; ++i) {
    float4 t = W4[(long)j * (H / 4) + q * 16 + i];
    wx[i] = t.x; wy[i] = t.y; wz[i] = t.z; ww[i] = t.w;
  }
  // Opaque-op barrier: values can no longer be rematerialized from memory.
#pragma unroll
  for (int i = 0; i < 16; ++i)
    asm volatile("" : "+v"(wx[i]), "+v"(wy[i]), "+v"(wz[i]), "+v"(ww[i]));

  if (tid < H) h_lds[tid] = 0.f;      // h0 = 0

  const long base = ((long)b * T) * H + j;
  float p0 = 0.f, p1 = 0.f;
  if (q == 0) { p0 = pre[base]; p1 = pre[base + H]; }
  __syncthreads();

  const float4* hv4 = (const float4*)h_lds;
#pragma unroll 1
  for (int t = 0; t < T; ++t) {
    float p2 = 0.f;
    if (q == 0 && t + 2 < T) p2 = pre[base + (long)(t + 2) * H];

    float ax = 0.f, ay = 0.f, az = 0.f, aw = 0.f;  // 4 chains
#pragma unroll
    for (int i = 0; i < 16; ++i) {
      float4 h4 = hv4[q * 16 + i];                 // b128 LDS broadcast
      ax += wx[i] * h4.x; ay += wy[i] * h4.y;
      az += wz[i] * h4.z; aw += ww[i] * h4.w;
    }
    part[q][j] = (ax + ay) + (az + aw);
    __syncthreads();
    if (q == 0) {
      float hn = tanhf(p0 + part[0][j] + part[1][j] + part[2][j] + part[3][j]);
      h_lds[j] = hn;
      hout[base + (long)t * H] = hn;               // coalesced 1KB
      p0 = p1; p1 = p2;
    }
    __syncthreads();
  }
}

// ---------------------------------------------------------------------------
// K5: out[m][p] = sigmoid( sum_j h2[m][j]*fcW[p][j] + fcb[p] )
// ---------------------------------------------------------------------------
__global__ __launch_bounds__(256) void fc_sigmoid(
    const float* __restrict__ h2, const float* __restrict__ fcW,
    const float* __restrict__ fcb, float* __restrict__ out) {
  __shared__ float h2l[16][H];        // 16 KB
  const int tid = threadIdx.x;
  const long m0 = (long)blockIdx.x * 16;

  const float4* H4 = (const float4*)h2;
#pragma unroll
  for (int i = 0; i < 4; ++i) {
    int idx = tid + 256 * i;
    int r = idx >> 6, c4 = idx & 63;
    *(float4*)&h2l[r][4 * c4] = H4[(m0 + r) * (H / 4) + c4];
  }
  __syncthreads();

  const int p = tid & 63, rq = tid >> 6;
  const float4* W4 = (const float4*)fcW;
  float acc[4] = {0.f, 0.f, 0.f, 0.f};
#pragma unroll 8
  for (int c4 = 0; c4 < H / 4; ++c4) {
    float4 wv = W4[(long)p * (H / 4) + c4];
#pragma unroll
    for (int k = 0; k < 4; ++k) {
      float4 av = *(const float4*)&h2l[rq * 4 + k][4 * c4];
      acc[k] += wv.x * av.x + wv.y * av.y + wv.z * av.z + wv.w * av.w;
    }
  }
  const float bb = fcb[p];
#pragma unroll
  for (int k = 0; k < 4; ++k) {
    float x = acc[k] + bb;
    out[(m0 + rq * 4 + k) * P + p] = 1.f / (1.f + __expf(-x));
  }
}

// ---------------------------------------------------------------------------
extern "C" void kernel_launch(void* const* d_in, const int* in_sizes, int n_in,
                              void* d_out, int out_size, void* d_ws, size_t ws_size,
                              hipStream_t stream) {
  const float* input = (const float*)d_in[0];
  const float* W_ih0 = (const float*)d_in[1];
  const float* W_hh0 = (const float*)d_in[2];
  const float* b_ih0 = (const float*)d_in[3];
  const float* b_hh0 = (const float*)d_in[4];
  const float* W_ih1 = (const float*)d_in[5];
  const float* W_hh1 = (const float*)d_in[6];
  const float* b_ih1 = (const float*)d_in[7];
  const float* b_hh1 = (const float*)d_in[8];
  const float* fc_W  = (const float*)d_in[9];
  const float* fc_b  = (const float*)d_in[10];
  float* out = (float*)d_out;

  float* bufA = (float*)d_ws;                 // pre0 -> pre1
  float* bufB = bufA + (size_t)M * H;         // h1 -> h2

  gemm_pre<IN><<<(int)(M / 16), 256, 0, stream>>>(input, W_ih0, b_ih0, b_hh0, bufA);
  rnn_scan<<<Bsz, 1024, 0, stream>>>(bufA, W_hh0, bufB);
  gemm_pre<H><<<(int)(M / 16), 256, 0, stream>>>(bufB, W_ih1, b_ih1, b_hh1, bufA);
  rnn_scan<<<Bsz, 1024, 0, stream>>>(bufA, W_hh1, bufB);
  fc_sigmoid<<<(int)(M / 16), 256, 0, stream>>>(bufB, fc_W, fc_b, out);
}

// Round 4
// 8223.943 us; speedup vs baseline: 1.1625x; 1.0626x over previous
//
#include <hip/hip_runtime.h>
#include <hip/hip_bf16.h>

// Problem constants (match reference)
constexpr int Bsz = 32;
constexpr int T   = 4096;
constexpr int P   = 64;
constexpr int IN  = 128;
constexpr int H   = 256;
constexpr long M  = (long)Bsz * T;   // 131072 rows

// ---------------------------------------------------------------------------
// K1/K3: out[m][j] = sum_c X[m][c] * W[j][c] + b1[j] + b2[j]
// ---------------------------------------------------------------------------
template <int K>
__global__ __launch_bounds__(256) void gemm_pre(
    const float* __restrict__ X, const float* __restrict__ W,
    const float* __restrict__ b1, const float* __restrict__ b2,
    float* __restrict__ out) {
  constexpr int K4 = K / 4;
  __shared__ float4 a4[16][K4];
  __shared__ float  wch[256][33];
  const int tid = threadIdx.x;
  const long m0 = (long)blockIdx.x * 16;

  const float4* X4 = (const float4*)X;
#pragma unroll
  for (int i = 0; i < (16 * K4) / 256; ++i) {
    int idx = tid + 256 * i;
    int r = idx / K4, c = idx % K4;
    a4[r][c] = X4[(m0 + r) * K4 + c];
  }

  const int j = tid;
  const float bsum = b1[j] + b2[j];
  float acc[16];
#pragma unroll
  for (int r = 0; r < 16; ++r) acc[r] = 0.f;

  const float4* W4v = (const float4*)W;
  for (int kc = 0; kc < K4; kc += 8) {
    __syncthreads();
#pragma unroll
    for (int i = 0; i < 8; ++i) {
      int idx = tid + 256 * i;
      int jr = idx >> 3, c = idx & 7;
      float4 t4 = W4v[(long)jr * K4 + kc + c];
      wch[jr][4 * c + 0] = t4.x; wch[jr][4 * c + 1] = t4.y;
      wch[jr][4 * c + 2] = t4.z; wch[jr][4 * c + 3] = t4.w;
    }
    __syncthreads();
#pragma unroll
    for (int i4 = 0; i4 < 8; ++i4) {
      float wx = wch[j][4 * i4 + 0], wy = wch[j][4 * i4 + 1];
      float wz = wch[j][4 * i4 + 2], ww = wch[j][4 * i4 + 3];
#pragma unroll
      for (int r = 0; r < 16; ++r) {
        float4 av = a4[r][kc + i4];
        acc[r] += wx * av.x + wy * av.y + wz * av.z + ww * av.w;
      }
    }
  }
#pragma unroll
  for (int r = 0; r < 16; ++r)
    out[(m0 + r) * H + j] = acc[r] + bsum;
}

// ---------------------------------------------------------------------------
// K2/K4: sequential scan. One WG (1024 thr, 16 waves) per batch element.
// Lane map: wave w owns 16 outputs; lane = jj(0..15) x kq(0..3) k-quarter.
// j = w*16+jj. Each thread holds W_hh[j][kq*64 .. +64) = 64 floats in VGPRs.
//  - spill fix (R3: VGPR=60 => w spilled to scratch): loads grouped 4-at-a-
//    time with sched_barrier(0) => peak pressure ~105 < 128; waves_per_eu(4,4)
//    pins the allocator target.
//  - k-partials reduced via __shfl_xor(16/32) butterfly (same wave) — no LDS
//    part[] round-trip; double-buffered h => ONE __syncthreads per step.
//  - tanh = 1 - 2*rcp(exp(2x)+1): ~5 VALU, exact at +-inf.
//  - h stored padded: quarter kq at word kq*68 => the 4-address b128
//    broadcast hits disjoint banks (68 mod 32 = 4) — conflict-free.
// ---------------------------------------------------------------------------
__global__ __attribute__((amdgpu_flat_work_group_size(1024, 1024),
                          amdgpu_waves_per_eu(4, 4)))
void rnn_scan(const float* __restrict__ pre, const float* __restrict__ W_hh,
              float* __restrict__ hout) {
  __shared__ float h_lds[2][4 * 68];   // double-buffered, quarter-padded

  const int tid  = threadIdx.x;
  const int lane = tid & 63;
  const int wv   = tid >> 6;           // 0..15
  const int jj   = lane & 15;
  const int kq   = lane >> 4;          // 0..3  (k-quarter)
  const int j    = (wv << 4) | jj;     // 0..255
  const int b    = blockIdx.x;

  // W_hh row j, quarter kq -> 64 floats in VGPRs
  const float4* W4 = (const float4*)W_hh;
  float wx[16], wy[16], wz[16], ww[16];
#pragma unroll
  for (int i = 0; i < 16; ++i) {
    float4 t = W4[(long)j * (H / 4) + kq * 16 + i];
    wx[i] = t.x; wy[i] = t.y; wz[i] = t.z; ww[i] = t.w;
  }
#pragma unroll
  for (int i = 0; i < 16; ++i)
    asm volatile("" : "+v"(wx[i]), "+v"(wy[i]), "+v"(wz[i]), "+v"(ww[i]));

  if (tid < 2 * 4 * 68) ((float*)h_lds)[tid] = 0.f;   // zero both buffers

  const long base   = (long)b * T * H + j;
  const float* prej = pre + base;
  float*       houtj = hout + base;
  float p0 = prej[0], p1 = prej[H];
  __syncthreads();

#pragma unroll 1
  for (int t = 0; t < T; ++t) {
    float p2 = (t + 2 < T) ? prej[(long)(t + 2) * H] : 0.f;  // dist-2 prefetch

    const float4* hb4 = (const float4*)(h_lds[t & 1] + kq * 68);
    float ax = 0.f, ay = 0.f, az = 0.f, aw = 0.f;
#pragma unroll
    for (int g = 0; g < 4; ++g) {       // 4 loads in flight max => no spill
      float4 h0 = hb4[4 * g + 0];
      float4 h1 = hb4[4 * g + 1];
      float4 h2 = hb4[4 * g + 2];
      float4 h3 = hb4[4 * g + 3];
      ax += wx[4 * g + 0] * h0.x; ay += wy[4 * g + 0] * h0.y;
      az += wz[4 * g + 0] * h0.z; aw += ww[4 * g + 0] * h0.w;
      ax += wx[4 * g + 1] * h1.x; ay += wy[4 * g + 1] * h1.y;
      az += wz[4 * g + 1] * h1.z; aw += ww[4 * g + 1] * h1.w;
      ax += wx[4 * g + 2] * h2.x; ay += wy[4 * g + 2] * h2.y;
      az += wz[4 * g + 2] * h2.z; aw += ww[4 * g + 2] * h2.w;
      ax += wx[4 * g + 3] * h3.x; ay += wy[4 * g + 3] * h3.y;
      az += wz[4 * g + 3] * h3.z; aw += ww[4 * g + 3] * h3.w;
      __builtin_amdgcn_sched_barrier(0);
    }
    float s = (ax + ay) + (az + aw);
    s += __shfl_xor(s, 16, 64);         // fold kq pairs
    s += __shfl_xor(s, 32, 64);         // all 4 kq lanes now hold full dot
    float x = p0 + s;
    float e = __expf(2.f * x);          // e^{2x} (native v_exp path)
    float hn = 1.f - 2.f * __builtin_amdgcn_rcpf(e + 1.f);  // tanh(x)

    if (kq == 0) {
      h_lds[(t + 1) & 1][(j >> 6) * 68 + (j & 63)] = hn;
      houtj[(long)t * H] = hn;          // 64B per wave, fire-and-forget
    }
    p0 = p1; p1 = p2;
    __syncthreads();                    // single barrier per step
  }
}

// ---------------------------------------------------------------------------
// K5: out[m][p] = sigmoid( sum_j h2[m][j]*fcW[p][j] + fcb[p] )
// ---------------------------------------------------------------------------
__global__ __launch_bounds__(256) void fc_sigmoid(
    const float* __restrict__ h2, const float* __restrict__ fcW,
    const float* __restrict__ fcb, float* __restrict__ out) {
  __shared__ float h2l[16][H];
  const int tid = threadIdx.x;
  const long m0 = (long)blockIdx.x * 16;

  const float4* H4 = (const float4*)h2;
#pragma unroll
  for (int i = 0; i < 4; ++i) {
    int idx = tid + 256 * i;
    int r = idx >> 6, c4 = idx & 63;
    *(float4*)&h2l[r][4 * c4] = H4[(m0 + r) * (H / 4) + c4];
  }
  __syncthreads();

  const int p = tid & 63, rq = tid >> 6;
  const float4* W4 = (const float4*)fcW;
  float acc[4] = {0.f, 0.f, 0.f, 0.f};
#pragma unroll 8
  for (int c4 = 0; c4 < H / 4; ++c4) {
    float4 wv = W4[(long)p * (H / 4) + c4];
#pragma unroll
    for (int k = 0; k < 4; ++k) {
      float4 av = *(const float4*)&h2l[rq * 4 + k][4 * c4];
      acc[k] += wv.x * av.x + wv.y * av.y + wv.z * av.z + wv.w * av.w;
    }
  }
  const float bb = fcb[p];
#pragma unroll
  for (int k = 0; k < 4; ++k) {
    float x = acc[k] + bb;
    out[(m0 + rq * 4 + k) * P + p] = 1.f / (1.f + __expf(-x));
  }
}

// ---------------------------------------------------------------------------
extern "C" void kernel_launch(void* const* d_in, const int* in_sizes, int n_in,
                              void* d_out, int out_size, void* d_ws, size_t ws_size,
                              hipStream_t stream) {
  const float* input = (const float*)d_in[0];
  const float* W_ih0 = (const float*)d_in[1];
  const float* W_hh0 = (const float*)d_in[2];
  const float* b_ih0 = (const float*)d_in[3];
  const float* b_hh0 = (const float*)d_in[4];
  const float* W_ih1 = (const float*)d_in[5];
  const float* W_hh1 = (const float*)d_in[6];
  const float* b_ih1 = (const float*)d_in[7];
  const float* b_hh1 = (const float*)d_in[8];
  const float* fc_W  = (const float*)d_in[9];
  const float* fc_b  = (const float*)d_in[10];
  float* out = (float*)d_out;

  float* bufA = (float*)d_ws;                 // pre0 -> pre1
  float* bufB = bufA + (size_t)M * H;         // h1 -> h2

  gemm_pre<IN><<<(int)(M / 16), 256, 0, stream>>>(input, W_ih0, b_ih0, b_hh0, bufA);
  rnn_scan<<<Bsz, 1024, 0, stream>>>(bufA, W_hh0, bufB);
  gemm_pre<H><<<(int)(M / 16), 256, 0, stream>>>(bufB, W_ih1, b_ih1, b_hh1, bufA);
  rnn_scan<<<Bsz, 1024, 0, stream>>>(bufA, W_hh1, bufB);
  fc_sigmoid<<<(int)(M / 16), 256, 0, stream>>>(bufB, fc_W, fc_b, out);
}